// Round 4
// baseline (181.749 us; speedup 1.0000x reference)
//
#include <hip/hip_runtime.h>

// ResidualGNNLayer: h = x@W; gcn_norm gather-aggregate (CSR built per-call);
// +bias; LayerNorm; 0.5*h+0.5*x; relu.  N=100000, E=300000, D=256.
//
// ws layout:
//   h     : N*256 bf16 (shorts)          51.2 MB
//   dv    : N floats  (deg -> dinv)       0.4 MB
//   cnt   : N ints    (in-degree)         0.4 MB
//   off   : N ints    (CSR offsets)       0.4 MB
//   cur   : N ints    (placement cursor)  0.4 MB
//   bsum  : 512 ints
//   elist : E int2    {src, coef}         2.4 MB
//   Wf    : 65536 shorts (fragment-major bf16 W)  128 KB

#define NN 100000
#define NE 300000
#define DD 256
#define NB 391   // ceil(NN/256)
#define GMB 782  // ceil(NN/128)

typedef __attribute__((ext_vector_type(8))) short short8;
typedef __attribute__((ext_vector_type(4))) short short4v;
typedef __attribute__((ext_vector_type(4))) float f32x4;
typedef __attribute__((ext_vector_type(4))) unsigned short u16x4;

static __device__ __forceinline__ short f2bf(float f) {
  union { float f; unsigned u; } a; a.f = f;
  unsigned r = a.u + 0x7fffu + ((a.u >> 16) & 1u);
  return (short)(r >> 16);
}

static __device__ __forceinline__ float4 bf4_to_f4(u16x4 v) {
  float4 r;
  r.x = __uint_as_float((unsigned)v[0] << 16);
  r.y = __uint_as_float((unsigned)v[1] << 16);
  r.z = __uint_as_float((unsigned)v[2] << 16);
  r.w = __uint_as_float((unsigned)v[3] << 16);
  return r;
}

__global__ __launch_bounds__(256) void k_init(float* __restrict__ dv,
                                              int* __restrict__ cnt) {
  int i = blockIdx.x * 256 + threadIdx.x;
  if (i < NN) { dv[i] = 0.0f; cnt[i] = 0; }
}

__global__ __launch_bounds__(256) void k_hist(const int* __restrict__ ei,
                                              const float* __restrict__ ew,
                                              float* __restrict__ dv,
                                              int* __restrict__ cnt) {
  int e = blockIdx.x * 256 + threadIdx.x;
  if (e < NE) {
    int d = ei[NE + e];
    atomicAdd(&dv[d], ew[e]);
    atomicAdd(&cnt[d], 1);
  }
}

__global__ __launch_bounds__(256) void k_dinv(float* __restrict__ dv) {
  int i = blockIdx.x * 256 + threadIdx.x;
  if (i < NN) dv[i] = rsqrtf(dv[i] + 1.0f);
}

__global__ __launch_bounds__(256) void k_scan1(const int* __restrict__ cnt,
                                               int* __restrict__ off,
                                               int* __restrict__ bsum) {
  __shared__ int tmp[256];
  int t = threadIdx.x;
  int i = blockIdx.x * 256 + t;
  int v = (i < NN) ? cnt[i] : 0;
  tmp[t] = v;
  __syncthreads();
  for (int o = 1; o < 256; o <<= 1) {
    int u = (t >= o) ? tmp[t - o] : 0;
    __syncthreads();
    tmp[t] += u;
    __syncthreads();
  }
  if (i < NN) off[i] = tmp[t] - v;
  if (t == 255) bsum[blockIdx.x] = tmp[t];
}

__global__ __launch_bounds__(512) void k_scan2(int* __restrict__ bsum) {
  __shared__ int tmp[512];
  int t = threadIdx.x;
  int v = (t < NB) ? bsum[t] : 0;
  tmp[t] = v;
  __syncthreads();
  for (int o = 1; o < 512; o <<= 1) {
    int u = (t >= o) ? tmp[t - o] : 0;
    __syncthreads();
    tmp[t] += u;
    __syncthreads();
  }
  bsum[t] = tmp[t] - v;
}

__global__ __launch_bounds__(256) void k_scan3(int* __restrict__ off,
                                               const int* __restrict__ bsum,
                                               int* __restrict__ cur) {
  int i = blockIdx.x * 256 + threadIdx.x;
  if (i < NN) {
    int o = off[i] + bsum[i >> 8];
    off[i] = o;
    cur[i] = o;
  }
}

__global__ __launch_bounds__(256) void k_place(const int* __restrict__ ei,
                                               const float* __restrict__ ew,
                                               const float* __restrict__ dv,
                                               int* __restrict__ cur,
                                               int2* __restrict__ elist) {
  int e = blockIdx.x * 256 + threadIdx.x;
  if (e >= NE) return;
  int s = ei[e];
  int d = ei[NE + e];
  float c = dv[s] * ew[e] * dv[d];
  int pos = atomicAdd(&cur[d], 1);
  elist[pos] = make_int2(s, __float_as_int(c));
}

// Pre-pack W (f32 [k][c]) into fragment-major bf16 Wf:
// short index = ((k>>5)*16 + (c>>4))*512 + ((c&15) + ((k>>3)&3)*16)*8 + (k&7)
__global__ __launch_bounds__(256) void k_wprep(const float* __restrict__ W,
                                               short* __restrict__ Wf) {
  int idx = blockIdx.x * 256 + threadIdx.x;  // 16384 total
  int k = idx >> 6;
  int c4 = idx & 63;
  const float4 v = *(const float4*)(W + k * 256 + c4 * 4);
  float vv[4] = {v.x, v.y, v.z, v.w};
#pragma unroll
  for (int i = 0; i < 4; ++i) {
    int c = c4 * 4 + i;
    int di = ((k >> 5) * 16 + (c >> 4)) * 512 + ((c & 15) + ((k >> 3) & 3) * 16) * 8 + (k & 7);
    Wf[di] = f2bf(vv[i]);
  }
}

// h = bf16(x @ W). BM=128, BN=256 (full), FULL K=256 staged once in LDS (64 KB).
// 8 waves (2x4). One barrier pair; 16 global loads in flight per thread during
// staging; 8 unrolled MFMA K-groups after, no barriers.
__global__ __launch_bounds__(512) void k_gemm(const float* __restrict__ x,
                                              const short* __restrict__ Wf,
                                              short* __restrict__ h) {
  __shared__ short As[128 * 256];  // 64 KB, XOR-swizzled rows (stride 512B)

  const int t = threadIdx.x;
  const int lane = t & 63;
  const int wid = t >> 6;
  const int row0 = blockIdx.x * 128;
  const int wrow = (wid >> 2) * 64;   // 0 or 64
  const int wcg = (wid & 3) * 4;      // col-group base (16-col units)

  // ---- stage full A tile: 128 rows x 256 k, f32 -> bf16, swizzled
#pragma unroll
  for (int i = 0; i < 8; ++i) {
    int p = i * 512 + t;   // 4096 chunks of 8 bf16
    int r = p >> 5;        // row 0..127
    int kp = p & 31;       // 8-elem chunk within row
    int grow = row0 + r;
    float4 v0 = make_float4(0.f, 0.f, 0.f, 0.f);
    float4 v1 = v0;
    if (grow < NN) {
      const float* src = x + (size_t)grow * 256 + kp * 8;
      v0 = *(const float4*)(src);
      v1 = *(const float4*)(src + 4);
    }
    short8 s;
    s[0] = f2bf(v0.x); s[1] = f2bf(v0.y); s[2] = f2bf(v0.z); s[3] = f2bf(v0.w);
    s[4] = f2bf(v1.x); s[5] = f2bf(v1.y); s[6] = f2bf(v1.z); s[7] = f2bf(v1.w);
    int byte = (r * 512 + kp * 16) ^ ((r & 7) << 4);
    *(short8*)((char*)As + byte) = s;
  }
  __syncthreads();

  f32x4 acc[4][4];
#pragma unroll
  for (int m = 0; m < 4; ++m)
#pragma unroll
    for (int n = 0; n < 4; ++n) acc[m][n] = (f32x4)0.0f;

#pragma unroll
  for (int ks = 0; ks < 8; ++ks) {
    short8 afrag[4];
    short8 bfrag[4];
#pragma unroll
    for (int m = 0; m < 4; ++m) {
      int r = wrow + m * 16 + (lane & 15);
      int byte = (r * 512 + ks * 64 + (lane >> 4) * 16) ^ ((r & 7) << 4);
      afrag[m] = *(short8*)((char*)As + byte);
    }
#pragma unroll
    for (int n = 0; n < 4; ++n) {
      size_t fi = (size_t)(ks * 16 + wcg + n) * 64 + lane;
      bfrag[n] = *(const short8*)(Wf + fi * 8);
    }
#pragma unroll
    for (int m = 0; m < 4; ++m)
#pragma unroll
      for (int n = 0; n < 4; ++n)
        acc[m][n] = __builtin_amdgcn_mfma_f32_16x16x32_bf16(
            afrag[m], bfrag[n], acc[m][n], 0, 0, 0);
  }

  // epilogue: h = bf16(acc). C/D layout: col = lane&15, row = 4*(lane>>4)+j
#pragma unroll
  for (int m = 0; m < 4; ++m) {
    int rbase = wrow + m * 16 + (lane >> 4) * 4;
#pragma unroll
    for (int j = 0; j < 4; ++j) {
      int grow = row0 + rbase + j;
      if (grow >= NN) continue;
#pragma unroll
      for (int n = 0; n < 4; ++n) {
        int c = (wcg + n) * 16 + (lane & 15);
        h[(size_t)grow * 256 + c] = f2bf(acc[m][n][j]);
      }
    }
  }
}

// gather-aggregate + self-loop + bias + LayerNorm + residual + relu.
__global__ __launch_bounds__(256) void k_agg(const short* __restrict__ h,
                                             const float* __restrict__ dv,
                                             const int* __restrict__ cnt,
                                             const int* __restrict__ off,
                                             const int2* __restrict__ elist,
                                             const float* __restrict__ x,
                                             const float* __restrict__ b,
                                             const float* __restrict__ gamma,
                                             const float* __restrict__ beta,
                                             float* __restrict__ out) {
  int node = blockIdx.x * 4 + (threadIdx.x >> 6);
  if (node >= NN) return;
  int lane = threadIdx.x & 63;

  const float di = dv[node];
  const float d2 = di * di;
  float4 acc = bf4_to_f4(((const u16x4*)(h + (size_t)node * 256))[lane]);
  acc.x *= d2; acc.y *= d2; acc.z *= d2; acc.w *= d2;

  const int n = cnt[node];
  const int st = off[node];
  if (n > 0) {
    int2 rec = elist[st];
    for (int j = 0; j < n; ++j) {
      int2 nrec = (j + 1 < n) ? elist[st + j + 1] : rec;
      float c = __int_as_float(rec.y);
      float4 v = bf4_to_f4(((const u16x4*)(h + (size_t)rec.x * 256))[lane]);
      acc.x += c * v.x; acc.y += c * v.y; acc.z += c * v.z; acc.w += c * v.w;
      rec = nrec;
    }
  }

  const float4 bb = *(const float4*)(b + lane * 4);
  acc.x += bb.x; acc.y += bb.y; acc.z += bb.z; acc.w += bb.w;

  float s = acc.x + acc.y + acc.z + acc.w;
  float ss = acc.x * acc.x + acc.y * acc.y + acc.z * acc.z + acc.w * acc.w;
#pragma unroll
  for (int o = 32; o > 0; o >>= 1) {
    s += __shfl_xor(s, o);
    ss += __shfl_xor(ss, o);
  }
  const float mu = s * (1.0f / 256.0f);
  const float var = ss * (1.0f / 256.0f) - mu * mu;
  const float inv = rsqrtf(var + 1e-5f);

  const float4 g = *(const float4*)(gamma + lane * 4);
  const float4 be = *(const float4*)(beta + lane * 4);
  const float4 xx = *(const float4*)(x + (size_t)node * 256 + lane * 4);
  float4 r;
  r.x = 0.5f * ((acc.x - mu) * inv * g.x + be.x) + 0.5f * xx.x;
  r.y = 0.5f * ((acc.y - mu) * inv * g.y + be.y) + 0.5f * xx.y;
  r.z = 0.5f * ((acc.z - mu) * inv * g.z + be.z) + 0.5f * xx.z;
  r.w = 0.5f * ((acc.w - mu) * inv * g.w + be.w) + 0.5f * xx.w;
  r.x = fmaxf(r.x, 0.0f); r.y = fmaxf(r.y, 0.0f);
  r.z = fmaxf(r.z, 0.0f); r.w = fmaxf(r.w, 0.0f);
  *(float4*)(out + (size_t)node * 256 + lane * 4) = r;
}

extern "C" void kernel_launch(void* const* d_in, const int* in_sizes, int n_in,
                              void* d_out, int out_size, void* d_ws, size_t ws_size,
                              hipStream_t stream) {
  const float* x     = (const float*)d_in[0];
  const int*   ei    = (const int*)d_in[1];
  const float* ew    = (const float*)d_in[2];
  const float* W     = (const float*)d_in[3];
  const float* b     = (const float*)d_in[4];
  const float* gamma = (const float*)d_in[5];
  const float* beta  = (const float*)d_in[6];
  float* out = (float*)d_out;

  short* h   = (short*)d_ws;                       // N*256 bf16
  float* dv  = (float*)(h + (size_t)NN * DD);      // N floats
  int*   cnt = (int*)(dv + NN);                    // N ints
  int*   off = cnt + NN;                           // N ints
  int*   cur = off + NN;                           // N ints
  int*   bsum = cur + NN;                          // 512 ints
  int2*  elist = (int2*)(bsum + 512);              // NE int2
  short* Wf  = (short*)(elist + NE);               // 65536 shorts

  k_init<<<NB, 256, 0, stream>>>(dv, cnt);
  k_hist<<<(NE + 255) / 256, 256, 0, stream>>>(ei, ew, dv, cnt);
  k_dinv<<<NB, 256, 0, stream>>>(dv);
  k_scan1<<<NB, 256, 0, stream>>>(cnt, off, bsum);
  k_scan2<<<1, 512, 0, stream>>>(bsum);
  k_scan3<<<NB, 256, 0, stream>>>(off, bsum, cur);
  k_place<<<(NE + 255) / 256, 256, 0, stream>>>(ei, ew, dv, cur, elist);

  k_wprep<<<64, 256, 0, stream>>>(W, Wf);
  k_gemm<<<GMB, 512, 0, stream>>>(x, Wf, h);

  k_agg<<<(NN + 3) / 4, 256, 0, stream>>>(h, dv, cnt, off, elist, x, b, gamma, beta, out);
}

// Round 5
// 172.734 us; speedup vs baseline: 1.0522x; 1.0522x over previous
//
#include <hip/hip_runtime.h>

// ResidualGNNLayer: h = x@W; gcn_norm gather-aggregate (CSR built per-call);
// +bias; LayerNorm; 0.5*h+0.5*x; relu.  N=100000, E=300000, D=256.
//
// ws layout:
//   h     : N*256 bf16 (shorts)          51.2 MB
//   dv    : N floats  (deg -> dinv)       0.4 MB
//   cnt   : N ints    (in-degree)         0.4 MB
//   off   : N ints    (CSR offsets)       0.4 MB
//   cur   : N ints    (placement cursor)  0.4 MB
//   bsum  : 512 ints
//   elist : E int2    {src, coef}         2.4 MB
//   Wf    : 65536 shorts (fragment-major bf16 W)  128 KB

#define NN 100000
#define NE 300000
#define DD 256
#define NB 391    // ceil(NN/256)
#define GMB 1563  // ceil(NN/64)

typedef __attribute__((ext_vector_type(8))) short short8;
typedef __attribute__((ext_vector_type(4))) short short4v;
typedef __attribute__((ext_vector_type(4))) float f32x4;
typedef __attribute__((ext_vector_type(4))) unsigned short u16x4;

static __device__ __forceinline__ short f2bf(float f) {
  union { float f; unsigned u; } a; a.f = f;
  unsigned r = a.u + 0x7fffu + ((a.u >> 16) & 1u);
  return (short)(r >> 16);
}

static __device__ __forceinline__ float bf2f(short s) {
  return __uint_as_float((unsigned)(unsigned short)s << 16);
}

__global__ __launch_bounds__(256) void k_init(float* __restrict__ dv,
                                              int* __restrict__ cnt) {
  int i = blockIdx.x * 256 + threadIdx.x;
  if (i < NN) { dv[i] = 0.0f; cnt[i] = 0; }
}

__global__ __launch_bounds__(256) void k_hist(const int* __restrict__ ei,
                                              const float* __restrict__ ew,
                                              float* __restrict__ dv,
                                              int* __restrict__ cnt) {
  int e = blockIdx.x * 256 + threadIdx.x;
  if (e < NE) {
    int d = ei[NE + e];
    atomicAdd(&dv[d], ew[e]);
    atomicAdd(&cnt[d], 1);
  }
}

__global__ __launch_bounds__(256) void k_dinv(float* __restrict__ dv) {
  int i = blockIdx.x * 256 + threadIdx.x;
  if (i < NN) dv[i] = rsqrtf(dv[i] + 1.0f);
}

__global__ __launch_bounds__(256) void k_scan1(const int* __restrict__ cnt,
                                               int* __restrict__ off,
                                               int* __restrict__ bsum) {
  __shared__ int tmp[256];
  int t = threadIdx.x;
  int i = blockIdx.x * 256 + t;
  int v = (i < NN) ? cnt[i] : 0;
  tmp[t] = v;
  __syncthreads();
  for (int o = 1; o < 256; o <<= 1) {
    int u = (t >= o) ? tmp[t - o] : 0;
    __syncthreads();
    tmp[t] += u;
    __syncthreads();
  }
  if (i < NN) off[i] = tmp[t] - v;
  if (t == 255) bsum[blockIdx.x] = tmp[t];
}

__global__ __launch_bounds__(512) void k_scan2(int* __restrict__ bsum) {
  __shared__ int tmp[512];
  int t = threadIdx.x;
  int v = (t < NB) ? bsum[t] : 0;
  tmp[t] = v;
  __syncthreads();
  for (int o = 1; o < 512; o <<= 1) {
    int u = (t >= o) ? tmp[t - o] : 0;
    __syncthreads();
    tmp[t] += u;
    __syncthreads();
  }
  bsum[t] = tmp[t] - v;
}

__global__ __launch_bounds__(256) void k_scan3(int* __restrict__ off,
                                               const int* __restrict__ bsum,
                                               int* __restrict__ cur) {
  int i = blockIdx.x * 256 + threadIdx.x;
  if (i < NN) {
    int o = off[i] + bsum[i >> 8];
    off[i] = o;
    cur[i] = o;
  }
}

__global__ __launch_bounds__(256) void k_place(const int* __restrict__ ei,
                                               const float* __restrict__ ew,
                                               const float* __restrict__ dv,
                                               int* __restrict__ cur,
                                               int2* __restrict__ elist) {
  int e = blockIdx.x * 256 + threadIdx.x;
  if (e >= NE) return;
  int s = ei[e];
  int d = ei[NE + e];
  float c = dv[s] * ew[e] * dv[d];
  int pos = atomicAdd(&cur[d], 1);
  elist[pos] = make_int2(s, __float_as_int(c));
}

// Pre-pack W (f32 [k][c]) into fragment-major bf16 Wf (same packing serves the
// A-operand role after the operand swap):
// short index = ((k>>5)*16 + (c>>4))*512 + ((c&15) + ((k>>3)&3)*16)*8 + (k&7)
__global__ __launch_bounds__(256) void k_wprep(const float* __restrict__ W,
                                               short* __restrict__ Wf) {
  int idx = blockIdx.x * 256 + threadIdx.x;  // 16384 total
  int k = idx >> 6;
  int c4 = idx & 63;
  const float4 v = *(const float4*)(W + k * 256 + c4 * 4);
  float vv[4] = {v.x, v.y, v.z, v.w};
#pragma unroll
  for (int i = 0; i < 4; ++i) {
    int c = c4 * 4 + i;
    int di = ((k >> 5) * 16 + (c >> 4)) * 512 + ((c & 15) + ((k >> 3) & 3) * 16) * 8 + (k & 7);
    Wf[di] = f2bf(vv[i]);
  }
}

// h = bf16(x @ W). BM=64, BN=256 (full), full K=256 staged once in LDS (32 KB).
// 8 waves (2 row x 4 col). OPERAND-SWAPPED MFMA: A = W-fragment (from Wf, L2),
// B = x-fragment (from LDS). D: row-index = W-col (4 consecutive per lane ->
// 8B packed stores), col-index = node row.
__global__ __launch_bounds__(512) void k_gemm(const float* __restrict__ x,
                                              const short* __restrict__ Wf,
                                              short* __restrict__ h) {
  __shared__ short As[64 * 256];  // 32 KB, rows 512B, XOR-swizzled

  const int t = threadIdx.x;
  const int lane = t & 63;
  const int wid = t >> 6;
  const int row0 = blockIdx.x * 64;
  const int wrow = (wid >> 2) * 32;        // node-row offset: 0 or 32
  const int wstrip = (wid & 3);            // 64-col strip

  // ---- stage A: load ALL first (8 independent dwordx4), then convert+write
  float4 va[4], vb[4];
#pragma unroll
  for (int i = 0; i < 4; ++i) {
    int p = i * 512 + t;          // 2048 chunks of 8 bf16
    int r = p >> 5;               // row 0..63
    int kp = p & 31;              // 8-elem chunk
    int grow = row0 + r;
    if (grow < NN) {
      const float* src = x + (size_t)grow * 256 + kp * 8;
      va[i] = *(const float4*)(src);
      vb[i] = *(const float4*)(src + 4);
    } else {
      va[i] = make_float4(0.f, 0.f, 0.f, 0.f);
      vb[i] = va[i];
    }
  }
#pragma unroll
  for (int i = 0; i < 4; ++i) {
    int p = i * 512 + t;
    int r = p >> 5;
    int kp = p & 31;
    short8 s;
    s[0] = f2bf(va[i].x); s[1] = f2bf(va[i].y); s[2] = f2bf(va[i].z); s[3] = f2bf(va[i].w);
    s[4] = f2bf(vb[i].x); s[5] = f2bf(vb[i].y); s[6] = f2bf(vb[i].z); s[7] = f2bf(vb[i].w);
    int byte = (r * 512 + kp * 16) ^ ((r & 7) << 4);
    *(short8*)((char*)As + byte) = s;
  }
  __syncthreads();

  f32x4 acc[4][2];
#pragma unroll
  for (int mc = 0; mc < 4; ++mc)
#pragma unroll
    for (int nr = 0; nr < 2; ++nr) acc[mc][nr] = (f32x4)0.0f;

  const short* wbase = Wf + (size_t)(wstrip * 4) * 512 + lane * 8;

#pragma unroll
  for (int ks = 0; ks < 8; ++ks) {
    short8 bx[2];   // x-side (B operand), from LDS
    short8 aw[4];   // W-side (A operand), from Wf (L2)
#pragma unroll
    for (int nr = 0; nr < 2; ++nr) {
      int r = wrow + nr * 16 + (lane & 15);
      int byte = (r * 512 + ks * 64 + (lane >> 4) * 16) ^ ((r & 7) << 4);
      bx[nr] = *(short8*)((char*)As + byte);
    }
#pragma unroll
    for (int mc = 0; mc < 4; ++mc)
      aw[mc] = *(const short8*)(wbase + (size_t)(ks * 16 + mc) * 512);
#pragma unroll
    for (int mc = 0; mc < 4; ++mc)
#pragma unroll
      for (int nr = 0; nr < 2; ++nr)
        acc[mc][nr] = __builtin_amdgcn_mfma_f32_16x16x32_bf16(
            aw[mc], bx[nr], acc[mc][nr], 0, 0, 0);
  }

  // ---- epilogue: D[row=W-col][col=node-row]; lane packs 4 consecutive cols.
#pragma unroll
  for (int mc = 0; mc < 4; ++mc) {
    int cbase = wstrip * 64 + mc * 16 + 4 * (lane >> 4);
#pragma unroll
    for (int nr = 0; nr < 2; ++nr) {
      int r = row0 + wrow + nr * 16 + (lane & 15);
      if (r < NN) {
        u16x4 s;
        s[0] = (unsigned short)f2bf(acc[mc][nr][0]);
        s[1] = (unsigned short)f2bf(acc[mc][nr][1]);
        s[2] = (unsigned short)f2bf(acc[mc][nr][2]);
        s[3] = (unsigned short)f2bf(acc[mc][nr][3]);
        *(u16x4*)(h + (size_t)r * 256 + cbase) = s;
      }
    }
  }
}

// gather-aggregate + self-loop + bias + LayerNorm + residual + relu.
// One node per 32-lane half-wave (2 nodes/wave); edge loop unrolled by 2.
__global__ __launch_bounds__(256) void k_agg(const short* __restrict__ h,
                                             const float* __restrict__ dv,
                                             const int* __restrict__ cnt,
                                             const int* __restrict__ off,
                                             const int2* __restrict__ elist,
                                             const float* __restrict__ x,
                                             const float* __restrict__ b,
                                             const float* __restrict__ gamma,
                                             const float* __restrict__ beta,
                                             float* __restrict__ out) {
  int node = (blockIdx.x * 256 + threadIdx.x) >> 5;
  if (node >= NN) return;
  int q = threadIdx.x & 31;           // sublane: features q*8 .. q*8+7

  const float di = dv[node];
  const float d2 = di * di;
  short8 hv = *(const short8*)(h + (size_t)node * 256 + q * 8);
  float a[8];
#pragma unroll
  for (int i = 0; i < 8; ++i) a[i] = bf2f(hv[i]) * d2;

  const int n = cnt[node];
  const int st = off[node];
  int j = 0;
  for (; j + 2 <= n; j += 2) {
    int2 r0 = elist[st + j];
    int2 r1 = elist[st + j + 1];
    short8 g0 = *(const short8*)(h + (size_t)r0.x * 256 + q * 8);
    short8 g1 = *(const short8*)(h + (size_t)r1.x * 256 + q * 8);
    float c0 = __int_as_float(r0.y);
    float c1 = __int_as_float(r1.y);
#pragma unroll
    for (int i = 0; i < 8; ++i) a[i] += c0 * bf2f(g0[i]);
#pragma unroll
    for (int i = 0; i < 8; ++i) a[i] += c1 * bf2f(g1[i]);
  }
  if (j < n) {
    int2 r0 = elist[st + j];
    short8 g0 = *(const short8*)(h + (size_t)r0.x * 256 + q * 8);
    float c0 = __int_as_float(r0.y);
#pragma unroll
    for (int i = 0; i < 8; ++i) a[i] += c0 * bf2f(g0[i]);
  }

  const float4 b0 = *(const float4*)(b + q * 8);
  const float4 b1 = *(const float4*)(b + q * 8 + 4);
  a[0] += b0.x; a[1] += b0.y; a[2] += b0.z; a[3] += b0.w;
  a[4] += b1.x; a[5] += b1.y; a[6] += b1.z; a[7] += b1.w;

  float s = 0.f, ss = 0.f;
#pragma unroll
  for (int i = 0; i < 8; ++i) { s += a[i]; ss += a[i] * a[i]; }
#pragma unroll
  for (int o = 16; o > 0; o >>= 1) {
    s += __shfl_xor(s, o);
    ss += __shfl_xor(ss, o);
  }
  const float mu = s * (1.0f / 256.0f);
  const float var = ss * (1.0f / 256.0f) - mu * mu;
  const float inv = rsqrtf(var + 1e-5f);

  const float4 g0 = *(const float4*)(gamma + q * 8);
  const float4 g1 = *(const float4*)(gamma + q * 8 + 4);
  const float4 e0 = *(const float4*)(beta + q * 8);
  const float4 e1 = *(const float4*)(beta + q * 8 + 4);
  const float4 x0 = *(const float4*)(x + (size_t)node * 256 + q * 8);
  const float4 x1 = *(const float4*)(x + (size_t)node * 256 + q * 8 + 4);

  float4 r0, r1;
  r0.x = fmaxf(0.5f * ((a[0] - mu) * inv * g0.x + e0.x) + 0.5f * x0.x, 0.f);
  r0.y = fmaxf(0.5f * ((a[1] - mu) * inv * g0.y + e0.y) + 0.5f * x0.y, 0.f);
  r0.z = fmaxf(0.5f * ((a[2] - mu) * inv * g0.z + e0.z) + 0.5f * x0.z, 0.f);
  r0.w = fmaxf(0.5f * ((a[3] - mu) * inv * g0.w + e0.w) + 0.5f * x0.w, 0.f);
  r1.x = fmaxf(0.5f * ((a[4] - mu) * inv * g1.x + e1.x) + 0.5f * x1.x, 0.f);
  r1.y = fmaxf(0.5f * ((a[5] - mu) * inv * g1.y + e1.y) + 0.5f * x1.y, 0.f);
  r1.z = fmaxf(0.5f * ((a[6] - mu) * inv * g1.z + e1.z) + 0.5f * x1.z, 0.f);
  r1.w = fmaxf(0.5f * ((a[7] - mu) * inv * g1.w + e1.w) + 0.5f * x1.w, 0.f);

  float* o = out + (size_t)node * 256 + q * 8;
  *(float4*)(o) = r0;
  *(float4*)(o + 4) = r1;
}

extern "C" void kernel_launch(void* const* d_in, const int* in_sizes, int n_in,
                              void* d_out, int out_size, void* d_ws, size_t ws_size,
                              hipStream_t stream) {
  const float* x     = (const float*)d_in[0];
  const int*   ei    = (const int*)d_in[1];
  const float* ew    = (const float*)d_in[2];
  const float* W     = (const float*)d_in[3];
  const float* b     = (const float*)d_in[4];
  const float* gamma = (const float*)d_in[5];
  const float* beta  = (const float*)d_in[6];
  float* out = (float*)d_out;

  short* h   = (short*)d_ws;                       // N*256 bf16
  float* dv  = (float*)(h + (size_t)NN * DD);      // N floats
  int*   cnt = (int*)(dv + NN);                    // N ints
  int*   off = cnt + NN;                           // N ints
  int*   cur = off + NN;                           // N ints
  int*   bsum = cur + NN;                          // 512 ints
  int2*  elist = (int2*)(bsum + 512);              // NE int2
  short* Wf  = (short*)(elist + NE);               // 65536 shorts

  k_init<<<NB, 256, 0, stream>>>(dv, cnt);
  k_hist<<<(NE + 255) / 256, 256, 0, stream>>>(ei, ew, dv, cnt);
  k_dinv<<<NB, 256, 0, stream>>>(dv);
  k_scan1<<<NB, 256, 0, stream>>>(cnt, off, bsum);
  k_scan2<<<1, 512, 0, stream>>>(bsum);
  k_scan3<<<NB, 256, 0, stream>>>(off, bsum, cur);
  k_place<<<(NE + 255) / 256, 256, 0, stream>>>(ei, ew, dv, cur, elist);

  k_wprep<<<64, 256, 0, stream>>>(W, Wf);
  k_gemm<<<GMB, 512, 0, stream>>>(x, Wf, h);

  k_agg<<<(NN * 32 + 255) / 256, 256, 0, stream>>>(h, dv, cnt, off, elist, x, b, gamma, beta, out);
}

// Round 6
// 164.761 us; speedup vs baseline: 1.1031x; 1.0484x over previous
//
#include <hip/hip_runtime.h>

// ResidualGNNLayer: h = x@W; gcn_norm gather-aggregate (CSR built per-call);
// +bias; LayerNorm; 0.5*h+0.5*x; relu.  N=100000, E=300000, D=256.
//
// ws layout:
//   h     : N*256 bf16 (shorts)          51.2 MB
//   dv    : N floats  (deg -> dinv)       0.4 MB
//   cnt   : N ints    (in-degree)         0.4 MB
//   off   : N ints    (CSR offsets)       0.4 MB
//   cur   : N ints    (placement cursor)  0.4 MB
//   bsum  : 512 ints
//   elist : E int2    {src, coef}         2.4 MB
//   Wf    : 65536 shorts (fragment-major bf16 W)  128 KB

#define NN 100000
#define NE 300000
#define DD 256
#define NB 391    // ceil(NN/256)
#define GMB 1563  // ceil(NN/64)

typedef __attribute__((ext_vector_type(8))) short short8;
typedef __attribute__((ext_vector_type(4))) float f32x4;
typedef __attribute__((ext_vector_type(4))) unsigned short u16x4;

static __device__ __forceinline__ short f2bf(float f) {
  union { float f; unsigned u; } a; a.f = f;
  unsigned r = a.u + 0x7fffu + ((a.u >> 16) & 1u);
  return (short)(r >> 16);
}

static __device__ __forceinline__ float bf2f(short s) {
  return __uint_as_float((unsigned)(unsigned short)s << 16);
}

__global__ __launch_bounds__(256) void k_init(float* __restrict__ dv,
                                              int* __restrict__ cnt) {
  int i = blockIdx.x * 256 + threadIdx.x;
  if (i < NN) { dv[i] = 0.0f; cnt[i] = 0; }
}

__global__ __launch_bounds__(256) void k_hist(const int* __restrict__ ei,
                                              const float* __restrict__ ew,
                                              float* __restrict__ dv,
                                              int* __restrict__ cnt) {
  int e = blockIdx.x * 256 + threadIdx.x;
  if (e < NE) {
    int d = ei[NE + e];
    atomicAdd(&dv[d], ew[e]);
    atomicAdd(&cnt[d], 1);
  }
}

__global__ __launch_bounds__(256) void k_dinv(float* __restrict__ dv) {
  int i = blockIdx.x * 256 + threadIdx.x;
  if (i < NN) dv[i] = rsqrtf(dv[i] + 1.0f);
}

__global__ __launch_bounds__(256) void k_scan1(const int* __restrict__ cnt,
                                               int* __restrict__ off,
                                               int* __restrict__ bsum) {
  __shared__ int tmp[256];
  int t = threadIdx.x;
  int i = blockIdx.x * 256 + t;
  int v = (i < NN) ? cnt[i] : 0;
  tmp[t] = v;
  __syncthreads();
  for (int o = 1; o < 256; o <<= 1) {
    int u = (t >= o) ? tmp[t - o] : 0;
    __syncthreads();
    tmp[t] += u;
    __syncthreads();
  }
  if (i < NN) off[i] = tmp[t] - v;
  if (t == 255) bsum[blockIdx.x] = tmp[t];
}

__global__ __launch_bounds__(512) void k_scan2(int* __restrict__ bsum) {
  __shared__ int tmp[512];
  int t = threadIdx.x;
  int v = (t < NB) ? bsum[t] : 0;
  tmp[t] = v;
  __syncthreads();
  for (int o = 1; o < 512; o <<= 1) {
    int u = (t >= o) ? tmp[t - o] : 0;
    __syncthreads();
    tmp[t] += u;
    __syncthreads();
  }
  bsum[t] = tmp[t] - v;
}

__global__ __launch_bounds__(256) void k_scan3(int* __restrict__ off,
                                               const int* __restrict__ bsum,
                                               int* __restrict__ cur) {
  int i = blockIdx.x * 256 + threadIdx.x;
  if (i < NN) {
    int o = off[i] + bsum[i >> 8];
    off[i] = o;
    cur[i] = o;
  }
}

__global__ __launch_bounds__(256) void k_place(const int* __restrict__ ei,
                                               const float* __restrict__ ew,
                                               const float* __restrict__ dv,
                                               int* __restrict__ cur,
                                               int2* __restrict__ elist) {
  int e = blockIdx.x * 256 + threadIdx.x;
  if (e >= NE) return;
  int s = ei[e];
  int d = ei[NE + e];
  float c = dv[s] * ew[e] * dv[d];
  int pos = atomicAdd(&cur[d], 1);
  elist[pos] = make_int2(s, __float_as_int(c));
}

// Pre-pack W (f32 [k][c]) into fragment-major bf16 Wf:
// short index = ((k>>5)*16 + (c>>4))*512 + ((c&15) + ((k>>3)&3)*16)*8 + (k&7)
__global__ __launch_bounds__(256) void k_wprep(const float* __restrict__ W,
                                               short* __restrict__ Wf) {
  int idx = blockIdx.x * 256 + threadIdx.x;  // 16384 total
  int k = idx >> 6;
  int c4 = idx & 63;
  const float4 v = *(const float4*)(W + k * 256 + c4 * 4);
  float vv[4] = {v.x, v.y, v.z, v.w};
#pragma unroll
  for (int i = 0; i < 4; ++i) {
    int c = c4 * 4 + i;
    int di = ((k >> 5) * 16 + (c >> 4)) * 512 + ((c & 15) + ((k >> 3) & 3) * 16) * 8 + (k & 7);
    Wf[di] = f2bf(vv[i]);
  }
}

// h = bf16(x @ W). BM=64, BN=256, K=256. 8 waves (2 row x 4 col strips).
// Operand-swapped MFMA (A = W frag from Wf/L2, B = x frag from LDS).
// Pipelined staging: 8 named float4 loads issued at top; LDS filled in 4
// K-regions; raw s_barrier with lgkmcnt(0) only (no vmcnt drain) so later
// regions' loads stay in flight under compute (T4 counted-vmcnt pattern).
__global__ __launch_bounds__(512, 2) void k_gemm(const float* __restrict__ x,
                                                 const short* __restrict__ Wf,
                                                 short* __restrict__ h) {
  __shared__ short As[64 * 256];  // 32 KB, rows 512B, XOR-swizzled

  const int t = threadIdx.x;
  const int lane = t & 63;
  const int wid = t >> 6;
  const int row0 = blockIdx.x * 64;
  const int wrow = (wid >> 2) * 32;   // node-row offset: 0 or 32
  const int wstrip = wid & 3;         // 64-col strip

  // ---- issue ALL staging loads (one row, one 8-elem chunk col, 4 K-regions)
  const int rr = t >> 3;   // row 0..63
  const int kc = t & 7;    // 8-elem chunk within a 64-k region
  int grow = row0 + rr;
  if (grow > NN - 1) grow = NN - 1;   // clamp; OOB rows discarded at store
  const float* rp = x + (size_t)grow * 256 + kc * 8;
  float4 a0 = *(const float4*)(rp);        float4 b0 = *(const float4*)(rp + 4);
  float4 a1 = *(const float4*)(rp + 64);   float4 b1 = *(const float4*)(rp + 68);
  float4 a2 = *(const float4*)(rp + 128);  float4 b2 = *(const float4*)(rp + 132);
  float4 a3 = *(const float4*)(rp + 192);  float4 b3 = *(const float4*)(rp + 196);

  // swizzled write byte for region 0; region i adds i*128 (XOR bits < 128)
  const int wb = (rr * 512 + kc * 16) ^ ((rr & 7) << 4);

#define WRITE_REGION(I, A, B)                                              \
  {                                                                        \
    short8 s_;                                                             \
    s_[0] = f2bf(A.x); s_[1] = f2bf(A.y); s_[2] = f2bf(A.z);               \
    s_[3] = f2bf(A.w); s_[4] = f2bf(B.x); s_[5] = f2bf(B.y);               \
    s_[6] = f2bf(B.z); s_[7] = f2bf(B.w);                                  \
    *(short8*)((char*)As + wb + (I)*128) = s_;                             \
  }

#define BARSYNC                                                            \
  asm volatile("s_waitcnt lgkmcnt(0)" ::: "memory");                       \
  __builtin_amdgcn_s_barrier();

  f32x4 acc[4][2];
#pragma unroll
  for (int mc = 0; mc < 4; ++mc)
#pragma unroll
    for (int nr = 0; nr < 2; ++nr) acc[mc][nr] = (f32x4)0.0f;

  const short* wbase = Wf + (size_t)(wstrip * 4) * 512 + lane * 8;

#define COMPUTE_REGION(I)                                                  \
  _Pragma("unroll")                                                        \
  for (int ks2 = 0; ks2 < 2; ++ks2) {                                      \
    const int ks = 2 * (I) + ks2;                                          \
    short8 bx[2];                                                          \
    short8 aw[4];                                                          \
    _Pragma("unroll")                                                      \
    for (int nr = 0; nr < 2; ++nr) {                                       \
      int r_ = wrow + nr * 16 + (lane & 15);                               \
      int byte_ = (r_ * 512 + ks * 64 + (lane >> 4) * 16) ^ ((r_ & 7) << 4); \
      bx[nr] = *(short8*)((char*)As + byte_);                              \
    }                                                                      \
    _Pragma("unroll")                                                      \
    for (int mc = 0; mc < 4; ++mc)                                         \
      aw[mc] = *(const short8*)(wbase + (size_t)(ks * 16 + mc) * 512);     \
    _Pragma("unroll")                                                      \
    for (int mc = 0; mc < 4; ++mc)                                         \
      _Pragma("unroll")                                                    \
      for (int nr = 0; nr < 2; ++nr)                                       \
        acc[mc][nr] = __builtin_amdgcn_mfma_f32_16x16x32_bf16(             \
            aw[mc], bx[nr], acc[mc][nr], 0, 0, 0);                         \
  }

  WRITE_REGION(0, a0, b0);
  BARSYNC;
  COMPUTE_REGION(0);
  WRITE_REGION(1, a1, b1);
  BARSYNC;
  COMPUTE_REGION(1);
  WRITE_REGION(2, a2, b2);
  BARSYNC;
  COMPUTE_REGION(2);
  WRITE_REGION(3, a3, b3);
  BARSYNC;
  COMPUTE_REGION(3);

#undef WRITE_REGION
#undef BARSYNC
#undef COMPUTE_REGION

  // ---- epilogue: D[row=W-col][col=node-row]; lane packs 4 consecutive cols.
#pragma unroll
  for (int mc = 0; mc < 4; ++mc) {
    int cbase = wstrip * 64 + mc * 16 + 4 * (lane >> 4);
#pragma unroll
    for (int nr = 0; nr < 2; ++nr) {
      int r = row0 + wrow + nr * 16 + (lane & 15);
      if (r < NN) {
        u16x4 s;
        s[0] = (unsigned short)f2bf(acc[mc][nr][0]);
        s[1] = (unsigned short)f2bf(acc[mc][nr][1]);
        s[2] = (unsigned short)f2bf(acc[mc][nr][2]);
        s[3] = (unsigned short)f2bf(acc[mc][nr][3]);
        *(u16x4*)(h + (size_t)r * 256 + cbase) = s;
      }
    }
  }
}

// gather-aggregate + self-loop + bias + LayerNorm + residual + relu.
// One node per 32-lane half-wave; edge loop unrolled by 4.
__global__ __launch_bounds__(256) void k_agg(const short* __restrict__ h,
                                             const float* __restrict__ dv,
                                             const int* __restrict__ cnt,
                                             const int* __restrict__ off,
                                             const int2* __restrict__ elist,
                                             const float* __restrict__ x,
                                             const float* __restrict__ b,
                                             const float* __restrict__ gamma,
                                             const float* __restrict__ beta,
                                             float* __restrict__ out) {
  int node = (blockIdx.x * 256 + threadIdx.x) >> 5;
  if (node >= NN) return;
  int q = threadIdx.x & 31;           // sublane: features q*8 .. q*8+7

  const float di = dv[node];
  const float d2 = di * di;
  short8 hv = *(const short8*)(h + (size_t)node * 256 + q * 8);
  float a[8];
#pragma unroll
  for (int i = 0; i < 8; ++i) a[i] = bf2f(hv[i]) * d2;

  const int n = cnt[node];
  const int st = off[node];
  int j = 0;
  for (; j + 4 <= n; j += 4) {
    int2 r0 = elist[st + j];
    int2 r1 = elist[st + j + 1];
    int2 r2 = elist[st + j + 2];
    int2 r3 = elist[st + j + 3];
    short8 g0 = *(const short8*)(h + (size_t)r0.x * 256 + q * 8);
    short8 g1 = *(const short8*)(h + (size_t)r1.x * 256 + q * 8);
    short8 g2 = *(const short8*)(h + (size_t)r2.x * 256 + q * 8);
    short8 g3 = *(const short8*)(h + (size_t)r3.x * 256 + q * 8);
    float c0 = __int_as_float(r0.y);
    float c1 = __int_as_float(r1.y);
    float c2 = __int_as_float(r2.y);
    float c3 = __int_as_float(r3.y);
#pragma unroll
    for (int i = 0; i < 8; ++i)
      a[i] += c0 * bf2f(g0[i]) + c1 * bf2f(g1[i]) + c2 * bf2f(g2[i]) + c3 * bf2f(g3[i]);
  }
  for (; j < n; ++j) {
    int2 r0 = elist[st + j];
    short8 g0 = *(const short8*)(h + (size_t)r0.x * 256 + q * 8);
    float c0 = __int_as_float(r0.y);
#pragma unroll
    for (int i = 0; i < 8; ++i) a[i] += c0 * bf2f(g0[i]);
  }

  const float4 b0 = *(const float4*)(b + q * 8);
  const float4 b1 = *(const float4*)(b + q * 8 + 4);
  a[0] += b0.x; a[1] += b0.y; a[2] += b0.z; a[3] += b0.w;
  a[4] += b1.x; a[5] += b1.y; a[6] += b1.z; a[7] += b1.w;

  float s = 0.f, ss = 0.f;
#pragma unroll
  for (int i = 0; i < 8; ++i) { s += a[i]; ss += a[i] * a[i]; }
#pragma unroll
  for (int o = 16; o > 0; o >>= 1) {
    s += __shfl_xor(s, o);
    ss += __shfl_xor(ss, o);
  }
  const float mu = s * (1.0f / 256.0f);
  const float var = ss * (1.0f / 256.0f) - mu * mu;
  const float inv = rsqrtf(var + 1e-5f);

  const float4 g0 = *(const float4*)(gamma + q * 8);
  const float4 g1 = *(const float4*)(gamma + q * 8 + 4);
  const float4 e0 = *(const float4*)(beta + q * 8);
  const float4 e1 = *(const float4*)(beta + q * 8 + 4);
  const float4 x0 = *(const float4*)(x + (size_t)node * 256 + q * 8);
  const float4 x1 = *(const float4*)(x + (size_t)node * 256 + q * 8 + 4);

  float4 r0, r1;
  r0.x = fmaxf(0.5f * ((a[0] - mu) * inv * g0.x + e0.x) + 0.5f * x0.x, 0.f);
  r0.y = fmaxf(0.5f * ((a[1] - mu) * inv * g0.y + e0.y) + 0.5f * x0.y, 0.f);
  r0.z = fmaxf(0.5f * ((a[2] - mu) * inv * g0.z + e0.z) + 0.5f * x0.z, 0.f);
  r0.w = fmaxf(0.5f * ((a[3] - mu) * inv * g0.w + e0.w) + 0.5f * x0.w, 0.f);
  r1.x = fmaxf(0.5f * ((a[4] - mu) * inv * g1.x + e1.x) + 0.5f * x1.x, 0.f);
  r1.y = fmaxf(0.5f * ((a[5] - mu) * inv * g1.y + e1.y) + 0.5f * x1.y, 0.f);
  r1.z = fmaxf(0.5f * ((a[6] - mu) * inv * g1.z + e1.z) + 0.5f * x1.z, 0.f);
  r1.w = fmaxf(0.5f * ((a[7] - mu) * inv * g1.w + e1.w) + 0.5f * x1.w, 0.f);

  float* o = out + (size_t)node * 256 + q * 8;
  *(float4*)(o) = r0;
  *(float4*)(o + 4) = r1;
}

extern "C" void kernel_launch(void* const* d_in, const int* in_sizes, int n_in,
                              void* d_out, int out_size, void* d_ws, size_t ws_size,
                              hipStream_t stream) {
  const float* x     = (const float*)d_in[0];
  const int*   ei    = (const int*)d_in[1];
  const float* ew    = (const float*)d_in[2];
  const float* W     = (const float*)d_in[3];
  const float* b     = (const float*)d_in[4];
  const float* gamma = (const float*)d_in[5];
  const float* beta  = (const float*)d_in[6];
  float* out = (float*)d_out;

  short* h   = (short*)d_ws;                       // N*256 bf16
  float* dv  = (float*)(h + (size_t)NN * DD);      // N floats
  int*   cnt = (int*)(dv + NN);                    // N ints
  int*   off = cnt + NN;                           // N ints
  int*   cur = off + NN;                           // N ints
  int*   bsum = cur + NN;                          // 512 ints
  int2*  elist = (int2*)(bsum + 512);              // NE int2
  short* Wf  = (short*)(elist + NE);               // 65536 shorts

  k_init<<<NB, 256, 0, stream>>>(dv, cnt);
  k_hist<<<(NE + 255) / 256, 256, 0, stream>>>(ei, ew, dv, cnt);
  k_dinv<<<NB, 256, 0, stream>>>(dv);
  k_scan1<<<NB, 256, 0, stream>>>(cnt, off, bsum);
  k_scan2<<<1, 512, 0, stream>>>(bsum);
  k_scan3<<<NB, 256, 0, stream>>>(off, bsum, cur);
  k_place<<<(NE + 255) / 256, 256, 0, stream>>>(ei, ew, dv, cur, elist);

  k_wprep<<<64, 256, 0, stream>>>(W, Wf);
  k_gemm<<<GMB, 512, 0, stream>>>(x, Wf, h);

  k_agg<<<(NN * 32 + 255) / 256, 256, 0, stream>>>(h, dv, cnt, off, elist, x, b, gamma, beta, out);
}